// Round 1
// baseline (69.989 us; speedup 1.0000x reference)
//
#include <hip/hip_runtime.h>
#include <math.h>

#define M_TOT 87296
#define NMAIN 682           // main blocks, 128 locations each; block NMAIN = pos-terms
#define INF_F 100000000.0f

// ws layout (floats):
//   [0        .. NMAIN)      per-block reg_sum
//   [NMAIN    .. 2*NMAIN)    per-block reg_cnt
//   [2*NMAIN  .. 3*NMAIN)    per-block neg_sum
//   [3*NMAIN], [3*NMAIN+1]   psum, pcnt (from pos-terms block)
// No counter/fence: finalize is a separate dispatch (stream-ordered, coherent at kernel boundary).

__global__ __launch_bounds__(256, 3) void main_kernel(
    const float* __restrict__ boxes,     // [4,64,4]
    const float* __restrict__ agn,       // [M_TOT]
    const float* __restrict__ reg_pred,  // [M_TOT,4]
    float* __restrict__ ws)
{
    __shared__ float4 sBox[256];
    __shared__ float  sRed[16];

    const int t   = threadIdx.x;
    const int blk = blockIdx.x;

    const int   LB_[5]   = {0, 65536, 81920, 86016, 87040};
    const int   locSh[5] = {14, 12, 10, 8, 6};
    const int   wSh[5]   = {7, 6, 5, 4, 3};
    const float SV[5]    = {8.f, 16.f, 32.f, 64.f, 128.f};
    const float LOv[5]   = {0.f, 64.f, 128.f, 256.f, 512.f};
    const float HIv[5]   = {80.f, 160.f, 320.f, 640.f, 10000000.f};

    if (blk == NMAIN) {
        // ---- pos-terms block (independent of the assignment) ----
        const int   LOC[5] = {16384, 4096, 1024, 256, 64};
        const int   WW[5]  = {128, 64, 32, 16, 8};
        float psum = 0.f, pcnt = 0.f;
        for (int j = t; j < 1280; j += 256) {     // [B,N,L] flattened, L fastest
            const int lev = j % 5;
            const int bn  = j / 5;
            const int b   = bn >> 6;
            const float4 bx = ((const float4*)boxes)[bn];
            const float cx = (bx.x + bx.z) * 0.5f;
            const float cy = (bx.y + bx.w) * 0.5f;
            const int cix = (int)(cx / SV[lev]);
            const int ciy = (int)(cy / SV[lev]);
            int pos = LB_[lev] + b * LOC[lev] + ciy * WW[lev] + cix;
            pos = min(max(pos, 0), M_TOT - 1);
            const float dx = bx.z - bx.x, dy = bx.w - bx.y;
            const float crit = sqrtf(dx * dx + dy * dy) * 0.5f;
            const bool msk = (crit >= LOv[lev]) && (crit <= HIv[lev]);
            const float z = agn[pos];
            float pp = 1.0f / (1.0f + expf(-z));
            pp = fminf(fmaxf(pp, 1e-4f), 1.0f - 1e-4f);
            if (msk) {
                const float om = 1.0f - pp;
                psum += logf(pp) * (om * om);
                pcnt += 1.0f;
            }
        }
        for (int off = 32; off; off >>= 1) {
            psum += __shfl_down(psum, off);
            pcnt += __shfl_down(pcnt, off);
        }
        if ((t & 63) == 0) { sRed[t >> 6] = psum; sRed[4 + (t >> 6)] = pcnt; }
        __syncthreads();
        if (t == 0) {
            ws[3 * NMAIN]     = sRed[0] + sRed[1] + sRed[2] + sRed[3];
            ws[3 * NMAIN + 1] = sRed[4] + sRed[5] + sRed[6] + sRed[7];
        }
        return;
    }

    // ---- main: 128 consecutive locations; 8 subs x 8 boxes x 4 locs per thread ----
    // Key structural facts exploited below:
    //  * a group's 4 locs are 4 consecutive x-positions in ONE row (all level widths
    //    divisible by 4, locBase multiple of 4) -> gy and every y-side term is
    //    j-invariant; x-terms advance by exactly j*s.
    //  * dx (vs quantized center) is an exact multiple of s/2 -> incremental dx is
    //    bit-exact; l/rr/ddx incremental form is <=1 ulp vs direct.
    const int mbase = blk << 7;
    int lev;
    if      (mbase < 65536) lev = 0;
    else if (mbase < 81920) lev = 1;
    else if (mbase < 86016) lev = 2;
    else if (mbase < 87040) lev = 3;
    else                    lev = 4;

    const int   LB    = LB_[lev];
    const int   lsh   = locSh[lev];
    const int   wsh   = wSh[lev];
    const float s     = SV[lev];
    const float inv_s = 1.0f / s;      // s is pow2: exact reciprocal
    const float half  = 0.5f * s;
    const float lo    = LOv[lev], hi = HIv[lev];

    sBox[t] = ((const float4*)boxes)[t];     // stage all 256 boxes
    __syncthreads();

    const int g       = t >> 3;              // 32 groups x 4 locations
    const int su      = t & 7;               // sub-lane: boxes su+8k
    const int locBase = mbase + g * 4;       // group's 4 locs lie in ONE image, ONE row
    const int imgBase = ((locBase - LB) >> lsh) << 6;
    const int p0      = (locBase - LB) & ((1 << lsh) - 1);
    const float gx0   = (float)(p0 & ((1 << wsh) - 1)) * s + half;   // exact
    const float gy    = (float)(p0 >> wsh) * s + half;               // exact, j-invariant

    // early epilogue loads: issue before the compute loop to hide latency
    float  zEarly  = 0.f;
    float4 pvEarly = make_float4(0.f, 0.f, 0.f, 0.f);
    if (su < 4) {
        zEarly  = agn[locBase + su];
        pvEarly = ((const float4*)reg_pred)[locBase + su];
    }

    const double DELTA = (1.0 - 0.8) / (1.0 + 0.8);
    const float  RADC  = (float)(DELTA * DELTA * 2.0);

    // per-box j-invariant state (7 floats + 2 predicate bits per box)
    float l0[8], rr0[8], ttbb[8], dx0[8], ddx0[8], ddy2[8], bir[8];
    bool  yok[8], ypk[8];
    #pragma unroll
    for (int k = 0; k < 8; ++k) {
        const float4 A = sBox[imgBase + su + 8 * k];
        const float bcx = (A.x + A.z) * 0.5f;
        const float bcy = (A.y + A.w) * 0.5f;
        const float bqx = truncf(bcx * inv_s) * s + half;   // int32-trunc semantics, centers>=0
        const float bqy = truncf(bcy * inv_s) * s + half;
        l0[k]  = gx0 - A.x;
        rr0[k] = A.z - gx0;
        const float tt = gy - A.y;
        const float bb = A.w - gy;
        ttbb[k] = fminf(tt, bb);
        dx0[k]  = gx0 - bqx;                 // exact multiple of s/2
        const float dyc = gy - bqy;          // exact
        ddx0[k] = gx0 - bcx;
        const float ddy = gy - bcy;
        ddy2[k] = ddy * ddy;
        const float bw = A.z - A.x, bh = A.w - A.y;
        const float area = bw * bh;
        bir[k] = 1.0f / fmaxf(RADC * area, 16.0f);
        const float crit = sqrtf(bw * bw + bh * bh) * 0.5f;  // level-uniform hoist (<=2ulp vs ref)
        yok[k] = (fabsf(dyc) <= s) && (crit >= lo) && (crit <= hi);
        ypk[k] = (dyc == 0.0f);
    }

    float minW[4], bestD[4];
    int   bestN[4];
    #pragma unroll
    for (int j = 0; j < 4; ++j) { minW[j] = INF_F; bestD[j] = INF_F; bestN[j] = 0; }

    #pragma unroll
    for (int k = 0; k < 8; ++k) {
        const float tb  = ttbb[k];
        const float b_  = bir[k];
        const float dy2 = ddy2[k];
        const bool  yk  = yok[k];
        const bool  pk  = ypk[k];
        const int   n   = su + 8 * k;
        #pragma unroll
        for (int j = 0; j < 4; ++j) {
            const float js  = (float)j * s;          // compile-time constant
            const float l   = l0[k] + js;
            const float rr  = rr0[k] - js;
            const float dx  = dx0[k] + js;           // exact
            const float ddx = ddx0[k] + js;
            const bool is_in = fminf(fminf(l, rr), tb) > 0.0f;
            const bool xok   = fabsf(dx) <= s;
            const bool peak  = (dx == 0.0f) && pk;
            const bool msk   = is_in && xok && yk;
            float dist2 = ddx * ddx + dy2;
            dist2 = peak ? 0.0f : dist2;
            const float w2 = dist2 * b_;
            minW[j] = fminf(minW[j], w2);
            const float d = msk ? w2 : INF_F;        // w2 < 1e8 always
            if (d < bestD[j]) { bestD[j] = d; bestN[j] = n; }  // ascending n: first-min
        }
    }

    // cross-sub reduce per slot j; lane su==j keeps -> lane covers loc locBase+su (su<4)
    unsigned long long myKey = ~0ULL; float myMinW = INF_F;
    #pragma unroll
    for (int j = 0; j < 4; ++j) {
        // nonneg float bits order-preserving: min key == (min d, then min n) == first-min
        unsigned long long kj =
            ((unsigned long long)__float_as_uint(bestD[j]) << 6) | (unsigned)bestN[j];
        float wj = minW[j];
        #pragma unroll
        for (int m = 1; m < 8; m <<= 1) {
            const unsigned long long o = __shfl_xor(kj, m);
            kj = o < kj ? o : kj;
            wj = fminf(wj, __shfl_xor(wj, m));
        }
        if (su == j) { myKey = kj; myMinW = wj; }
    }

    float neg_term = 0.f, reg_term = 0.f, reg_val = 0.f;
    if (su < 4) {
        float hmv = expf(-myMinW);
        if (hmv < 1e-4f) hmv = 0.0f;
        const float u = 1.0f - hmv;
        const float neg_w = (u * u) * (u * u);
        float pr = 1.0f / (1.0f + expf(-zEarly));
        pr = fminf(fmaxf(pr, 1e-4f), 1.0f - 1e-4f);
        if (pr < 0.85f) neg_term = logf(1.0f - pr) * (pr * pr) * neg_w;

        if ((unsigned)(myKey >> 6) < __float_as_uint(INF_F)) {
            reg_val = 1.0f;
            const int n = (int)(myKey & 63);
            const float4 A = sBox[imgBase + n];
            const int   px = (p0 & ((1 << wsh) - 1)) + su;   // same row, no wrap
            const float gx = (float)px * s + half;           // exact == ref grid value
            const float tl  = (gx - A.x) * inv_s;    // bit-exact vs /s
            const float tt2 = (gy - A.y) * inv_s;
            const float tr  = (A.z - gx) * inv_s;
            const float tb2 = (A.w - gy) * inv_s;
            const float pl = pvEarly.x, pt = pvEarly.y, prr = pvEarly.z, pb = pvEarly.w;
            const float target_area = (tl + tr) * (tt2 + tb2);
            const float pred_area   = (pl + prr) * (pt + pb);
            const float w_i = fminf(pl, tl) + fminf(prr, tr);
            const float g_w = fmaxf(pl, tl) + fmaxf(prr, tr);
            const float h_i = fminf(pb, tb2) + fminf(pt, tt2);
            const float g_h = fmaxf(pb, tb2) + fmaxf(pt, tt2);
            const float ac    = g_w * g_h + 1e-7f;
            const float inter = w_i * h_i;
            const float uni   = target_area + pred_area - inter;
            const float ious  = (inter + 1.0f) / (uni + 1.0f);
            const float gious = ious - (ac - uni) / ac;
            reg_term = 1.0f - gious;
        }
    }

    float r0 = reg_term, r1 = reg_val, r2 = neg_term;
    for (int off = 32; off; off >>= 1) {
        r0 += __shfl_down(r0, off);
        r1 += __shfl_down(r1, off);
        r2 += __shfl_down(r2, off);
    }
    if ((t & 63) == 0) {
        const int w = t >> 6;
        sRed[w * 3 + 0] = r0; sRed[w * 3 + 1] = r1; sRed[w * 3 + 2] = r2;
    }
    __syncthreads();
    if (t == 0) {
        ws[blk]             = sRed[0] + sRed[3] + sRed[6] + sRed[9];
        ws[NMAIN + blk]     = sRed[1] + sRed[4] + sRed[7] + sRed[10];
        ws[2 * NMAIN + blk] = sRed[2] + sRed[5] + sRed[8] + sRed[11];
    }
}

__global__ __launch_bounds__(256) void finalize(
    const float* __restrict__ ws,
    float* __restrict__ out)
{
    const int t = threadIdx.x;
    float racc = 0.f, cacc = 0.f, nacc = 0.f;
    for (int j = t; j < NMAIN; j += 256) {
        racc += ws[j];
        cacc += ws[NMAIN + j];
        nacc += ws[2 * NMAIN + j];
    }
    for (int off = 32; off; off >>= 1) {
        racc += __shfl_down(racc, off);
        cacc += __shfl_down(cacc, off);
        nacc += __shfl_down(nacc, off);
    }
    __shared__ float sr[4][3];
    if ((t & 63) == 0) {
        const int w = t >> 6;
        sr[w][0] = racc; sr[w][1] = cacc; sr[w][2] = nacc;
    }
    __syncthreads();
    if (t == 0) {
        const float RS = sr[0][0] + sr[1][0] + sr[2][0] + sr[3][0];
        const float RC = sr[0][1] + sr[1][1] + sr[2][1] + sr[3][1];
        const float NS = sr[0][2] + sr[1][2] + sr[2][2] + sr[3][2];
        const float PS = ws[3 * NMAIN];
        const float PC = ws[3 * NMAIN + 1];
        const float num_pos  = fmaxf(PC, 1.0f);
        const float reg_norm = fmaxf(RC, 1.0f);
        out[0] = RS / reg_norm;                     // REG_WEIGHT = 1
        out[1] = 0.5f * (0.25f * -PS) / num_pos;    // POS_W * ALPHA
        out[2] = 0.5f * (0.75f * -NS) / num_pos;    // NEG_W * (1-ALPHA)
    }
}

extern "C" void kernel_launch(void* const* d_in, const int* in_sizes, int n_in,
                              void* d_out, int out_size, void* d_ws, size_t ws_size,
                              hipStream_t stream) {
    const float* boxes    = (const float*)d_in[0];   // [4,64,4] f32
    // d_in[1] = gt_classes (unused)
    const float* agn      = (const float*)d_in[2];   // [87296] f32
    const float* reg_pred = (const float*)d_in[3];   // [87296,4] f32
    float* out = (float*)d_out;
    float* ws  = (float*)d_ws;

    main_kernel<<<NMAIN + 1, 256, 0, stream>>>(boxes, agn, reg_pred, ws);
    finalize<<<1, 256, 0, stream>>>(ws, out);
}